// Round 1
// baseline (124.488 us; speedup 1.0000x reference)
//
#include <hip/hip_runtime.h>
#include <math.h>

#define NSPLIT 4

// Per-Gaussian precompute: A = inv(R diag(s^2) R^T + eps I), fold -0.5*log2(e)
// into the quadratic-form coefficients so the hot loop is pure FMA + exp2.
__global__ __launch_bounds__(256) void gbf_precompute(
    const float* __restrict__ positions,
    const float* __restrict__ log_scales,
    const float* __restrict__ rotations,
    const float* __restrict__ weights,
    float* __restrict__ params, int N)
{
    int i = blockIdx.x * 256 + threadIdx.x;
    if (i >= N) return;

    float s0 = expf(log_scales[3*i+0]);
    float s1 = expf(log_scales[3*i+1]);
    float s2 = expf(log_scales[3*i+2]);
    float v0 = s0*s0, v1 = s1*s1, v2 = s2*s2;

    float qw = rotations[4*i+0], qx = rotations[4*i+1];
    float qy = rotations[4*i+2], qz = rotations[4*i+3];
    float nrm = sqrtf(qw*qw + qx*qx + qy*qy + qz*qz) + 1e-8f;
    float inv = 1.0f / nrm;
    qw *= inv; qx *= inv; qy *= inv; qz *= inv;

    float r00 = 1.f - 2.f*(qy*qy + qz*qz);
    float r01 = 2.f*(qx*qy - qz*qw);
    float r02 = 2.f*(qx*qz + qy*qw);
    float r10 = 2.f*(qx*qy + qz*qw);
    float r11 = 1.f - 2.f*(qx*qx + qz*qz);
    float r12 = 2.f*(qy*qz - qx*qw);
    float r20 = 2.f*(qx*qz - qy*qw);
    float r21 = 2.f*(qy*qz + qx*qw);
    float r22 = 1.f - 2.f*(qx*qx + qy*qy);

    // cov = R diag(v) R^T + eps I, symmetric [[a,b,c],[b,d,e],[c,e,f]]
    float a = r00*r00*v0 + r01*r01*v1 + r02*r02*v2 + 1e-6f;
    float b = r00*r10*v0 + r01*r11*v1 + r02*r12*v2;
    float c = r00*r20*v0 + r01*r21*v1 + r02*r22*v2;
    float d = r10*r10*v0 + r11*r11*v1 + r12*r12*v2 + 1e-6f;
    float e = r10*r20*v0 + r11*r21*v1 + r12*r22*v2;
    float f = r20*r20*v0 + r21*r21*v1 + r22*r22*v2 + 1e-6f;

    // symmetric 3x3 inverse via adjugate
    float m00 = d*f - e*e;
    float m01 = c*e - b*f;
    float m02 = b*e - c*d;
    float det = a*m00 + b*m01 + c*m02;
    float id  = 1.0f / det;
    float A00 = m00*id, A01 = m01*id, A02 = m02*id;
    float A11 = (a*f - c*c)*id;
    float A12 = (c*b - a*e)*id;
    float A22 = (a*d - b*b)*id;

    float ux = positions[3*i+0], uy = positions[3*i+1], uz = positions[3*i+2];
    float bx = A00*ux + A01*uy + A02*uz;
    float by = A01*ux + A11*uy + A12*uz;
    float bz = A02*ux + A12*uy + A22*uz;
    float cq = ux*bx + uy*by + uz*bz;

    const float kk = -0.72134752044448170368f; // -0.5 * log2(e)
    float* P = params + 12*i;
    P[0]  = kk*A00;      P[1]  = kk*A11;      P[2]  = kk*A22;      P[3] = 2.f*kk*A01;
    P[4]  = 2.f*kk*A02;  P[5]  = 2.f*kk*A12;  P[6]  = -2.f*kk*bx;  P[7] = -2.f*kk*by;
    P[8]  = -2.f*kk*bz;  P[9]  = kk*cq;       P[10] = weights[i];  P[11] = 0.f;
}

// Hot loop: per point, per Gaussian: exponent = Q:pp^T + L.p + C (9 FMA, 2 ADD),
// then acc += W * exp2(exponent). Params address is loop-uniform -> scalar loads.
__global__ __launch_bounds__(256) void gbf_eval(
    const float* __restrict__ points,
    const float4* __restrict__ params,
    float* __restrict__ out, int M, int nPer)
{
    int pt = blockIdx.x * 256 + threadIdx.x;
    if (pt >= M) return;
    float x = points[3*pt+0], y = points[3*pt+1], z = points[3*pt+2];
    float x2 = x*x, y2 = y*y, z2 = z*z;
    float xy = x*y, xz = x*z, yz = y*z;

    int base = blockIdx.y * nPer * 3;
    float acc = 0.f;
#pragma unroll 4
    for (int j = 0; j < nPer; ++j) {
        float4 q0 = params[base + 3*j + 0]; // Q00,Q11,Q22,Q01
        float4 q1 = params[base + 3*j + 1]; // Q02,Q12,Lx,Ly
        float4 q2 = params[base + 3*j + 2]; // Lz,C,W,pad

        float t0 = fmaf(q0.x, x2, q2.y);
        t0 = fmaf(q0.w, xy, t0);
        t0 = fmaf(q1.z, x,  t0);
        float t1 = q0.y * y2;
        t1 = fmaf(q1.y, yz, t1);
        t1 = fmaf(q1.w, y,  t1);
        float t2 = q0.z * z2;
        t2 = fmaf(q1.x, xz, t2);
        t2 = fmaf(q2.x, z,  t2);
        float e2 = (t0 + t1) + t2;
#if __has_builtin(__builtin_amdgcn_exp2f)
        float g = __builtin_amdgcn_exp2f(e2);
#else
        float g = exp2f(e2);
#endif
        acc = fmaf(q2.z, g, acc);
    }
    atomicAdd(&out[pt], acc);
}

extern "C" void kernel_launch(void* const* d_in, const int* in_sizes, int n_in,
                              void* d_out, int out_size, void* d_ws, size_t ws_size,
                              hipStream_t stream)
{
    const float* points     = (const float*)d_in[0];
    const float* positions  = (const float*)d_in[1];
    const float* log_scales = (const float*)d_in[2];
    const float* rotations  = (const float*)d_in[3];
    const float* weights    = (const float*)d_in[4];
    int M = in_sizes[0] / 3;
    int N = in_sizes[4];

    float* params = (float*)d_ws;          // N x 12 floats = 96 KB
    float* out    = (float*)d_out;

    hipMemsetAsync(d_out, 0, (size_t)out_size * sizeof(float), stream);

    gbf_precompute<<<dim3((N + 255) / 256), dim3(256), 0, stream>>>(
        positions, log_scales, rotations, weights, params, N);

    int nPer = N / NSPLIT;
    dim3 grid((M + 255) / 256, NSPLIT);
    gbf_eval<<<grid, dim3(256), 0, stream>>>(points, (const float4*)params, out, M, nPer);
}

// Round 2
// 62.017 us; speedup vs baseline: 2.0073x; 2.0073x over previous
//
#include <hip/hip_runtime.h>
#include <math.h>

#define NSPLIT 16   // grid-y splits of N -> 128 blocks.x * 16 = 2048 blocks = 8/CU
#define COARSEN 2   // points per thread

// Per-Gaussian precompute: A = inv(R diag(s^2) R^T + eps I), fold -0.5*log2(e)
// into the quadratic-form coefficients so the hot loop is pure FMA + exp2.
__global__ __launch_bounds__(256) void gbf_precompute(
    const float* __restrict__ positions,
    const float* __restrict__ log_scales,
    const float* __restrict__ rotations,
    const float* __restrict__ weights,
    float* __restrict__ params, int N)
{
    int i = blockIdx.x * 256 + threadIdx.x;
    if (i >= N) return;

    float s0 = expf(log_scales[3*i+0]);
    float s1 = expf(log_scales[3*i+1]);
    float s2 = expf(log_scales[3*i+2]);
    float v0 = s0*s0, v1 = s1*s1, v2 = s2*s2;

    float qw = rotations[4*i+0], qx = rotations[4*i+1];
    float qy = rotations[4*i+2], qz = rotations[4*i+3];
    float nrm = sqrtf(qw*qw + qx*qx + qy*qy + qz*qz) + 1e-8f;
    float inv = 1.0f / nrm;
    qw *= inv; qx *= inv; qy *= inv; qz *= inv;

    float r00 = 1.f - 2.f*(qy*qy + qz*qz);
    float r01 = 2.f*(qx*qy - qz*qw);
    float r02 = 2.f*(qx*qz + qy*qw);
    float r10 = 2.f*(qx*qy + qz*qw);
    float r11 = 1.f - 2.f*(qx*qx + qz*qz);
    float r12 = 2.f*(qy*qz - qx*qw);
    float r20 = 2.f*(qx*qz - qy*qw);
    float r21 = 2.f*(qy*qz + qx*qw);
    float r22 = 1.f - 2.f*(qx*qx + qy*qy);

    // cov = R diag(v) R^T + eps I, symmetric [[a,b,c],[b,d,e],[c,e,f]]
    float a = r00*r00*v0 + r01*r01*v1 + r02*r02*v2 + 1e-6f;
    float b = r00*r10*v0 + r01*r11*v1 + r02*r12*v2;
    float c = r00*r20*v0 + r01*r21*v1 + r02*r22*v2;
    float d = r10*r10*v0 + r11*r11*v1 + r12*r12*v2 + 1e-6f;
    float e = r10*r20*v0 + r11*r21*v1 + r12*r22*v2;
    float f = r20*r20*v0 + r21*r21*v1 + r22*r22*v2 + 1e-6f;

    // symmetric 3x3 inverse via adjugate
    float m00 = d*f - e*e;
    float m01 = c*e - b*f;
    float m02 = b*e - c*d;
    float det = a*m00 + b*m01 + c*m02;
    float id  = 1.0f / det;
    float A00 = m00*id, A01 = m01*id, A02 = m02*id;
    float A11 = (a*f - c*c)*id;
    float A12 = (c*b - a*e)*id;
    float A22 = (a*d - b*b)*id;

    float ux = positions[3*i+0], uy = positions[3*i+1], uz = positions[3*i+2];
    float bx = A00*ux + A01*uy + A02*uz;
    float by = A01*ux + A11*uy + A12*uz;
    float bz = A02*ux + A12*uy + A22*uz;
    float cq = ux*bx + uy*by + uz*bz;

    const float kk = -0.72134752044448170368f; // -0.5 * log2(e)
    float* P = params + 12*i;
    P[0]  = kk*A00;      P[1]  = kk*A11;      P[2]  = kk*A22;      P[3] = 2.f*kk*A01;
    P[4]  = 2.f*kk*A02;  P[5]  = 2.f*kk*A12;  P[6]  = -2.f*kk*bx;  P[7] = -2.f*kk*by;
    P[8]  = -2.f*kk*bz;  P[9]  = kk*cq;       P[10] = weights[i];  P[11] = 0.f;
}

// Hot loop: 2 points/thread, per Gaussian: exponent = Q:pp^T + L.p + C
// (9 FMA + 2 ADD per point), then acc += W * exp2(exponent).
// Params address is loop-uniform -> scalar s_load_dwordx4 broadcasts.
__global__ __launch_bounds__(256, 8) void gbf_eval(
    const float* __restrict__ points,
    const float4* __restrict__ params,
    float* __restrict__ out, int M, int nPer)
{
    int ptA = blockIdx.x * (256 * COARSEN) + threadIdx.x;
    int ptB = ptA + 256;
    if (ptB >= M) { if (ptA >= M) return; ptB = ptA; } // degenerate guard (M=65536 exact)

    float xa = points[3*ptA+0], ya = points[3*ptA+1], za = points[3*ptA+2];
    float xb = points[3*ptB+0], yb = points[3*ptB+1], zb = points[3*ptB+2];
    float xa2 = xa*xa, ya2 = ya*ya, za2 = za*za, xya = xa*ya, xza = xa*za, yza = ya*za;
    float xb2 = xb*xb, yb2 = yb*yb, zb2 = zb*zb, xyb = xb*yb, xzb = xb*zb, yzb = yb*zb;

    int base = blockIdx.y * nPer * 3;
    float accA = 0.f, accB = 0.f;
#pragma unroll 4
    for (int j = 0; j < nPer; ++j) {
        float4 q0 = params[base + 3*j + 0]; // Q00,Q11,Q22,Q01
        float4 q1 = params[base + 3*j + 1]; // Q02,Q12,Lx,Ly
        float4 q2 = params[base + 3*j + 2]; // Lz,C,W,pad

        float t0 = fmaf(q0.x, xa2, q2.y);
        t0 = fmaf(q0.w, xya, t0);
        t0 = fmaf(q1.z, xa,  t0);
        float t1 = q0.y * ya2;
        t1 = fmaf(q1.y, yza, t1);
        t1 = fmaf(q1.w, ya,  t1);
        float t2 = q0.z * za2;
        t2 = fmaf(q1.x, xza, t2);
        t2 = fmaf(q2.x, za,  t2);
        float eA = (t0 + t1) + t2;

        float u0 = fmaf(q0.x, xb2, q2.y);
        u0 = fmaf(q0.w, xyb, u0);
        u0 = fmaf(q1.z, xb,  u0);
        float u1 = q0.y * yb2;
        u1 = fmaf(q1.y, yzb, u1);
        u1 = fmaf(q1.w, yb,  u1);
        float u2 = q0.z * zb2;
        u2 = fmaf(q1.x, xzb, u2);
        u2 = fmaf(q2.x, zb,  u2);
        float eB = (u0 + u1) + u2;

#if __has_builtin(__builtin_amdgcn_exp2f)
        float gA = __builtin_amdgcn_exp2f(eA);
        float gB = __builtin_amdgcn_exp2f(eB);
#else
        float gA = exp2f(eA);
        float gB = exp2f(eB);
#endif
        accA = fmaf(q2.z, gA, accA);
        accB = fmaf(q2.z, gB, accB);
    }
    atomicAdd(&out[ptA], accA);
    if (ptB != ptA) atomicAdd(&out[ptB], accB);
}

extern "C" void kernel_launch(void* const* d_in, const int* in_sizes, int n_in,
                              void* d_out, int out_size, void* d_ws, size_t ws_size,
                              hipStream_t stream)
{
    const float* points     = (const float*)d_in[0];
    const float* positions  = (const float*)d_in[1];
    const float* log_scales = (const float*)d_in[2];
    const float* rotations  = (const float*)d_in[3];
    const float* weights    = (const float*)d_in[4];
    int M = in_sizes[0] / 3;
    int N = in_sizes[4];

    float* params = (float*)d_ws;          // N x 12 floats = 96 KB
    float* out    = (float*)d_out;

    hipMemsetAsync(d_out, 0, (size_t)out_size * sizeof(float), stream);

    gbf_precompute<<<dim3((N + 255) / 256), dim3(256), 0, stream>>>(
        positions, log_scales, rotations, weights, params, N);

    int nPer = N / NSPLIT;
    dim3 grid((M + 256 * COARSEN - 1) / (256 * COARSEN), NSPLIT);
    gbf_eval<<<grid, dim3(256), 0, stream>>>(points, (const float4*)params, out, M, nPer);
}

// Round 3
// 49.662 us; speedup vs baseline: 2.5067x; 1.2488x over previous
//
#include <hip/hip_runtime.h>
#include <math.h>

#define NSPLIT 32   // grid-y splits of N
#define COARSEN 4   // points per thread (2 packed float2 pairs)

typedef float v2f __attribute__((ext_vector_type(2)));

static __device__ __forceinline__ v2f s2(float s) { v2f r; r.x = s; r.y = s; return r; }
static __device__ __forceinline__ v2f pkfma(v2f a, v2f b, v2f c) {
    return __builtin_elementwise_fma(a, b, c);
}

// Per-Gaussian precompute: A = inv(R diag(s^2) R^T + eps I), fold -0.5*log2(e)
// into the quadratic-form coefficients so the hot loop is pure FMA + exp2.
__global__ __launch_bounds__(256) void gbf_precompute(
    const float* __restrict__ positions,
    const float* __restrict__ log_scales,
    const float* __restrict__ rotations,
    const float* __restrict__ weights,
    float* __restrict__ params, int N)
{
    int i = blockIdx.x * 256 + threadIdx.x;
    if (i >= N) return;

    float s0 = expf(log_scales[3*i+0]);
    float s1 = expf(log_scales[3*i+1]);
    float s2_ = expf(log_scales[3*i+2]);
    float v0 = s0*s0, v1 = s1*s1, v2 = s2_*s2_;

    float qw = rotations[4*i+0], qx = rotations[4*i+1];
    float qy = rotations[4*i+2], qz = rotations[4*i+3];
    float nrm = sqrtf(qw*qw + qx*qx + qy*qy + qz*qz) + 1e-8f;
    float inv = 1.0f / nrm;
    qw *= inv; qx *= inv; qy *= inv; qz *= inv;

    float r00 = 1.f - 2.f*(qy*qy + qz*qz);
    float r01 = 2.f*(qx*qy - qz*qw);
    float r02 = 2.f*(qx*qz + qy*qw);
    float r10 = 2.f*(qx*qy + qz*qw);
    float r11 = 1.f - 2.f*(qx*qx + qz*qz);
    float r12 = 2.f*(qy*qz - qx*qw);
    float r20 = 2.f*(qx*qz - qy*qw);
    float r21 = 2.f*(qy*qz + qx*qw);
    float r22 = 1.f - 2.f*(qx*qx + qy*qy);

    float a = r00*r00*v0 + r01*r01*v1 + r02*r02*v2 + 1e-6f;
    float b = r00*r10*v0 + r01*r11*v1 + r02*r12*v2;
    float c = r00*r20*v0 + r01*r21*v1 + r02*r22*v2;
    float d = r10*r10*v0 + r11*r11*v1 + r12*r12*v2 + 1e-6f;
    float e = r10*r20*v0 + r11*r21*v1 + r12*r22*v2;
    float f = r20*r20*v0 + r21*r21*v1 + r22*r22*v2 + 1e-6f;

    float m00 = d*f - e*e;
    float m01 = c*e - b*f;
    float m02 = b*e - c*d;
    float det = a*m00 + b*m01 + c*m02;
    float id  = 1.0f / det;
    float A00 = m00*id, A01 = m01*id, A02 = m02*id;
    float A11 = (a*f - c*c)*id;
    float A12 = (c*b - a*e)*id;
    float A22 = (a*d - b*b)*id;

    float ux = positions[3*i+0], uy = positions[3*i+1], uz = positions[3*i+2];
    float bx = A00*ux + A01*uy + A02*uz;
    float by = A01*ux + A11*uy + A12*uz;
    float bz = A02*ux + A12*uy + A22*uz;
    float cq = ux*bx + uy*by + uz*bz;

    const float kk = -0.72134752044448170368f; // -0.5 * log2(e)
    float* P = params + 12*i;
    P[0]  = kk*A00;      P[1]  = kk*A11;      P[2]  = kk*A22;      P[3] = 2.f*kk*A01;
    P[4]  = 2.f*kk*A02;  P[5]  = 2.f*kk*A12;  P[6]  = -2.f*kk*bx;  P[7] = -2.f*kk*by;
    P[8]  = -2.f*kk*bz;  P[9]  = kk*cq;       P[10] = weights[i];  P[11] = 0.f;
}

// Hot loop: 4 points/thread as 2 packed float2 pairs. Per Gaussian per pair:
// 11 v_pk_* ops + 1 pk acc + 2 v_exp_f32. Params loads are wave-uniform ->
// scalar s_load_dwordx4, broadcast into VOP3P sgpr operands.
__global__ __launch_bounds__(256, 8) void gbf_eval(
    const float* __restrict__ points,
    const float4* __restrict__ params,
    float* __restrict__ out, int M, int nPer)
{
    int p0 = blockIdx.x * (256 * COARSEN) + threadIdx.x;
    int p1 = p0 + 256, p2 = p0 + 512, p3 = p0 + 768;
    int c0 = min(p0, M-1), c1 = min(p1, M-1), c2 = min(p2, M-1), c3 = min(p3, M-1);

    v2f X1, Y1, Z1, X2_, Y2_, Z2_;
    X1.x = points[3*c0+0]; X1.y = points[3*c1+0];
    Y1.x = points[3*c0+1]; Y1.y = points[3*c1+1];
    Z1.x = points[3*c0+2]; Z1.y = points[3*c1+2];
    X2_.x = points[3*c2+0]; X2_.y = points[3*c3+0];
    Y2_.x = points[3*c2+1]; Y2_.y = points[3*c3+1];
    Z2_.x = points[3*c2+2]; Z2_.y = points[3*c3+2];

    v2f XX1 = X1*X1, YY1 = Y1*Y1, ZZ1 = Z1*Z1;
    v2f XY1 = X1*Y1, XZ1 = X1*Z1, YZ1 = Y1*Z1;
    v2f XX2 = X2_*X2_, YY2 = Y2_*Y2_, ZZ2 = Z2_*Z2_;
    v2f XY2 = X2_*Y2_, XZ2 = X2_*Z2_, YZ2 = Y2_*Z2_;

    int base = blockIdx.y * nPer * 3;
    v2f acc1; acc1.x = 0.f; acc1.y = 0.f;
    v2f acc2 = acc1;

#pragma unroll 2
    for (int j = 0; j < nPer; ++j) {
        float4 q0 = params[base + 3*j + 0]; // Q00,Q11,Q22,Q01
        float4 q1 = params[base + 3*j + 1]; // Q02,Q12,Lx,Ly
        float4 q2 = params[base + 3*j + 2]; // Lz,C,W,pad

        v2f t0 = pkfma(s2(q0.x), XX1, s2(q2.y));
        t0 = pkfma(s2(q0.w), XY1, t0);
        t0 = pkfma(s2(q1.z), X1,  t0);
        v2f t1 = s2(q0.y) * YY1;
        t1 = pkfma(s2(q1.y), YZ1, t1);
        t1 = pkfma(s2(q1.w), Y1,  t1);
        v2f t2 = s2(q0.z) * ZZ1;
        t2 = pkfma(s2(q1.x), XZ1, t2);
        t2 = pkfma(s2(q2.x), Z1,  t2);
        v2f e1 = (t0 + t1) + t2;

        v2f u0 = pkfma(s2(q0.x), XX2, s2(q2.y));
        u0 = pkfma(s2(q0.w), XY2, u0);
        u0 = pkfma(s2(q1.z), X2_, u0);
        v2f u1 = s2(q0.y) * YY2;
        u1 = pkfma(s2(q1.y), YZ2, u1);
        u1 = pkfma(s2(q1.w), Y2_, u1);
        v2f u2 = s2(q0.z) * ZZ2;
        u2 = pkfma(s2(q1.x), XZ2, u2);
        u2 = pkfma(s2(q2.x), Z2_, u2);
        v2f e2 = (u0 + u1) + u2;

        v2f g1, g2;
#if __has_builtin(__builtin_amdgcn_exp2f)
        g1.x = __builtin_amdgcn_exp2f(e1.x); g1.y = __builtin_amdgcn_exp2f(e1.y);
        g2.x = __builtin_amdgcn_exp2f(e2.x); g2.y = __builtin_amdgcn_exp2f(e2.y);
#else
        g1.x = exp2f(e1.x); g1.y = exp2f(e1.y);
        g2.x = exp2f(e2.x); g2.y = exp2f(e2.y);
#endif
        acc1 = pkfma(s2(q2.z), g1, acc1);
        acc2 = pkfma(s2(q2.z), g2, acc2);
    }
    if (p0 < M) atomicAdd(&out[p0], acc1.x);
    if (p1 < M) atomicAdd(&out[p1], acc1.y);
    if (p2 < M) atomicAdd(&out[p2], acc2.x);
    if (p3 < M) atomicAdd(&out[p3], acc2.y);
}

extern "C" void kernel_launch(void* const* d_in, const int* in_sizes, int n_in,
                              void* d_out, int out_size, void* d_ws, size_t ws_size,
                              hipStream_t stream)
{
    const float* points     = (const float*)d_in[0];
    const float* positions  = (const float*)d_in[1];
    const float* log_scales = (const float*)d_in[2];
    const float* rotations  = (const float*)d_in[3];
    const float* weights    = (const float*)d_in[4];
    int M = in_sizes[0] / 3;
    int N = in_sizes[4];

    float* params = (float*)d_ws;          // N x 12 floats = 96 KB
    float* out    = (float*)d_out;

    hipMemsetAsync(d_out, 0, (size_t)out_size * sizeof(float), stream);

    gbf_precompute<<<dim3((N + 255) / 256), dim3(256), 0, stream>>>(
        positions, log_scales, rotations, weights, params, N);

    int nPer = N / NSPLIT;
    dim3 grid((M + 256 * COARSEN - 1) / (256 * COARSEN), NSPLIT);
    gbf_eval<<<grid, dim3(256), 0, stream>>>(points, (const float4*)params, out, M, nPer);
}